// Round 1
// baseline (1145.862 us; speedup 1.0000x reference)
//
#include <hip/hip_runtime.h>
#include <math.h>

#define H 128
#define W 128
#define HW (H*W)
#define BATCH 2

__device__ __forceinline__ float sigmoidf_(float x){ return 1.0f/(1.0f + expf(-x)); }

// ---------------------------------------------------------------------------
// Kernel 1/6: 3x3 conv (pad 1) producing 18 offset channels + 9 sigmoid(mask)
// channels. Each thread computes 3 consecutive output channels for one pixel.
// g in 0..5 -> offset channels 3g..3g+2 (weights wp), g in 6..8 -> mask
// channels (weights wm, sigmoid applied).
// out layout: [B][27][HW]  (0..17 offsets, 18..26 mask)
// ---------------------------------------------------------------------------
template<int CIN>
__global__ __launch_bounds__(256) void conv_offmask(
    const float* __restrict__ x,    // [B][CIN][HW]
    const float* __restrict__ wp,   // [18][CIN][3][3]
    const float* __restrict__ bp,   // [18]
    const float* __restrict__ wm,   // [9][CIN][3][3]
    const float* __restrict__ bm,   // [9]
    float* __restrict__ out)        // [B][27][HW]
{
    int t = blockIdx.x * 256 + threadIdx.x;
    if (t >= BATCH * HW * 9) return;
    int g   = t / (BATCH * HW);
    int r   = t - g * (BATCH * HW);
    int b   = r >> 14;
    int pix = r & (HW - 1);
    int i = pix >> 7, j = pix & (W - 1);

    bool ismask = (g >= 6);
    const float* wbase = ismask ? (wm + (size_t)(g - 6) * 3 * CIN * 9)
                                : (wp + (size_t)g * 3 * CIN * 9);
    float a0 = 0.f, a1 = 0.f, a2 = 0.f;
    const float* xb = x + (size_t)b * CIN * HW;
    for (int c = 0; c < CIN; c++) {
        const float* xp = xb + (size_t)c * HW;
        const float* wc = wbase + c * 9;
        #pragma unroll
        for (int di = 0; di < 3; di++) {
            int ii = i + di - 1;
            if (ii < 0 || ii >= H) continue;
            #pragma unroll
            for (int dj = 0; dj < 3; dj++) {
                int jj = j + dj - 1;
                if (jj < 0 || jj >= W) continue;
                float xv = xp[ii * W + jj];
                int wi = di * 3 + dj;
                a0 = fmaf(xv, wc[wi], a0);
                a1 = fmaf(xv, wc[CIN * 9 + wi], a1);
                a2 = fmaf(xv, wc[2 * CIN * 9 + wi], a2);
            }
        }
    }
    int oc;
    if (ismask) {
        int o0 = (g - 6) * 3;
        a0 = sigmoidf_(a0 + bm[o0]);
        a1 = sigmoidf_(a1 + bm[o0 + 1]);
        a2 = sigmoidf_(a2 + bm[o0 + 2]);
        oc = 18 + o0;
    } else {
        int o0 = g * 3;
        a0 += bp[o0]; a1 += bp[o0 + 1]; a2 += bp[o0 + 2];
        oc = o0;
    }
    float* ob = out + ((size_t)b * 27 + oc) * HW + pix;
    ob[0] = a0; ob[HW] = a1; ob[2 * HW] = a2;
}

// ---------------------------------------------------------------------------
// Kernel 2/7: deformable sampling + main 3x3 conv (stride-ks trick) fused as a
// per-pixel matmul out[o] = sum_k w[o][k] * s[k], k = c*9+n,
// s[k] = mask_n * bilinear(src_c, p_n).  Block: 8 pixels (same row), 256 thr.
// ---------------------------------------------------------------------------
template<int CIN>
__global__ __launch_bounds__(256) void deform_conv(
    const float* __restrict__ src,   // [B][CIN][HW]
    const float* __restrict__ off,   // [B][27][HW]
    const float* __restrict__ wmain, // [64][CIN*9]
    float* __restrict__ out)         // [B][64][HW]
{
    constexpr int K = CIN * 9;
    constexpr int PIX = 8;
    __shared__ __align__(16) float s[PIX][68];    // sample chunk (64 + pad)
    __shared__ __align__(16) float wl[64][68];    // weight chunk [o][k'] (+pad)
    __shared__ int   midx[PIX][9][4];
    __shared__ float mwt[PIX][9][4];
    __shared__ __align__(16) float obuf[PIX * 64];

    int tid  = threadIdx.x;
    int pix0 = blockIdx.x * PIX;          // linear pixel index b*HW + i*W + j0
    int b    = pix0 >> 14;
    int base = pix0 & (HW - 1);
    int i    = base >> 7;
    int j0   = base & (W - 1);

    // ---- phase 0: bilinear metadata for PIX*9 sample points -------------
    if (tid < PIX * 9) {
        int p = tid / 9, n = tid - (tid / 9) * 9;
        int j = j0 + p;
        int pix = (i << 7) + j;
        const float* ob = off + (size_t)b * 27 * HW + pix;
        float px = ob[(size_t)n * HW]       + (float)(n / 3 - 1) + (float)(i + 1);
        float py = ob[(size_t)(9 + n) * HW] + (float)(n % 3 - 1) + (float)(j + 1);
        float mk = ob[(size_t)(18 + n) * HW];
        float fx = floorf(px), fy = floorf(py);
        const float lim = 129.0f;            // Hp-1 = Wp-1 = 129
        int qltx = (int)fminf(fmaxf(fx, 0.f), lim);
        int qlty = (int)fminf(fmaxf(fy, 0.f), lim);
        int qrbx = (int)fminf(fmaxf(fx + 1.f, 0.f), lim);
        int qrby = (int)fminf(fmaxf(fy + 1.f, 0.f), lim);
        float pxc = fminf(fmaxf(px, 0.f), lim);
        float pyc = fminf(fmaxf(py, 0.f), lim);
        float gxl = 1.f + ((float)qltx - pxc);
        float gxr = 1.f - ((float)qrbx - pxc);
        float gyl = 1.f + ((float)qlty - pyc);
        float gyr = 1.f - ((float)qrby - pyc);
        int   xs[4] = {qltx, qrbx, qltx, qrbx};
        int   ys[4] = {qlty, qrby, qrby, qlty};
        float gs[4] = {gxl * gyl, gxr * gyr, gxl * gyr, gxr * gyl};
        #pragma unroll
        for (int r = 0; r < 4; r++) {
            int qx = xs[r], qy = ys[r];
            bool valid = (qx >= 1 && qx <= H && qy >= 1 && qy <= W);
            midx[p][n][r] = valid ? ((qx - 1) * W + (qy - 1)) : -1;
            mwt[p][n][r]  = gs[r] * mk;
        }
    }
    __syncthreads();

    int wv = tid >> 6;        // wave id 0..3 -> pixels 2*wv, 2*wv+1
    int o  = tid & 63;        // output channel
    float acc0 = 0.f, acc1 = 0.f;
    const float* srcb = src + (size_t)b * CIN * HW;

    for (int kk = 0; kk < K; kk += 64) {
        // stage weight chunk: wl[oo][kp] = wmain[oo][kk+kp]
        #pragma unroll
        for (int r = 0; r < 16; r++) {
            int idx = r * 256 + tid;
            int oo = idx >> 6, kp = idx & 63;
            wl[oo][kp] = wmain[(size_t)oo * K + kk + kp];
        }
        // sample chunk: s[p][kq], 8 lanes per (c,n) spanning the 8 pixels
        #pragma unroll
        for (int r = 0; r < 2; r++) {
            int id = r * 256 + tid;
            int p  = id & 7;
            int kq = id >> 3;
            int k  = kk + kq;
            int c  = k / 9;
            int n  = k - c * 9;
            const float* plane = srcb + (size_t)c * HW;
            const int*   ix = midx[p][n];
            const float* gw = mwt[p][n];
            float v = 0.f;
            #pragma unroll
            for (int r3 = 0; r3 < 4; r3++) {
                int idx2 = ix[r3];
                float xv = (idx2 >= 0) ? plane[idx2] : 0.f;
                v = fmaf(xv, gw[r3], v);
            }
            s[p][kq] = v;
        }
        __syncthreads();
        // matmul chunk: each lane does 64 k for 2 pixels
        const float4* wrow = reinterpret_cast<const float4*>(&wl[o][0]);
        const float4* s0p  = reinterpret_cast<const float4*>(&s[2 * wv][0]);
        const float4* s1p  = reinterpret_cast<const float4*>(&s[2 * wv + 1][0]);
        #pragma unroll
        for (int q = 0; q < 16; q++) {
            float4 w4 = wrow[q];
            float4 v0 = s0p[q];
            float4 v1 = s1p[q];
            acc0 = fmaf(w4.x, v0.x, acc0); acc0 = fmaf(w4.y, v0.y, acc0);
            acc0 = fmaf(w4.z, v0.z, acc0); acc0 = fmaf(w4.w, v0.w, acc0);
            acc1 = fmaf(w4.x, v1.x, acc1); acc1 = fmaf(w4.y, v1.y, acc1);
            acc1 = fmaf(w4.z, v1.z, acc1); acc1 = fmaf(w4.w, v1.w, acc1);
        }
        __syncthreads();
    }

    // ---- transpose through LDS for coalesced-ish stores -----------------
    obuf[o * 8 + 2 * wv]     = acc0;
    obuf[o * 8 + 2 * wv + 1] = acc1;
    __syncthreads();
    {
        int o2 = tid >> 2;
        int pp = (tid & 3) * 2;
        float2 val = *reinterpret_cast<float2*>(&obuf[tid * 2]);
        float* op = out + ((size_t)b * 64 + o2) * HW + (i << 7) + j0 + pp;
        op[0] = val.x; op[1] = val.y;
    }
}

// ---------------------------------------------------------------------------
// Kernel 3/8: group-norm statistics. One block per (b, group); group = 4
// consecutive channels -> contiguous 64K-float region.
// stats[bg] = mean, stats[32+bg] = rstd
// ---------------------------------------------------------------------------
__global__ __launch_bounds__(256) void gn_stats(
    const float* __restrict__ buf, float* __restrict__ stats)
{
    int bg = blockIdx.x;                       // 0..31
    const float4* v = reinterpret_cast<const float4*>(buf + (size_t)bg * 4 * HW);
    float sum = 0.f, ssq = 0.f;
    for (int idx = threadIdx.x; idx < 4 * HW / 4; idx += 256) {
        float4 x = v[idx];
        sum += x.x + x.y + x.z + x.w;
        ssq += x.x * x.x + x.y * x.y + x.z * x.z + x.w * x.w;
    }
    #pragma unroll
    for (int d = 32; d > 0; d >>= 1) {
        sum += __shfl_down(sum, d);
        ssq += __shfl_down(ssq, d);
    }
    __shared__ float ws1[4], ws2[4];
    int wid = threadIdx.x >> 6;
    if ((threadIdx.x & 63) == 0) { ws1[wid] = sum; ws2[wid] = ssq; }
    __syncthreads();
    if (threadIdx.x == 0) {
        float S = ws1[0] + ws1[1] + ws1[2] + ws1[3];
        float Q = ws2[0] + ws2[1] + ws2[2] + ws2[3];
        float mean = S * (1.0f / (4.0f * HW));
        float var  = Q * (1.0f / (4.0f * HW)) - mean * mean;
        stats[bg]      = mean;
        stats[32 + bg] = rsqrtf(var + 1e-5f);
    }
}

// ---------------------------------------------------------------------------
// Kernel 4: apply GN+relu -> c1, and produce channel mean & max maps.
// ---------------------------------------------------------------------------
__global__ __launch_bounds__(256) void gn_apply_meanmax(
    const float* __restrict__ dc, const float* __restrict__ stats,
    const float* __restrict__ gamma, const float* __restrict__ beta,
    float* __restrict__ c1, float* __restrict__ cm, float* __restrict__ cx)
{
    int t = blockIdx.x * 256 + threadIdx.x;
    if (t >= BATCH * HW) return;
    int b = t >> 14;
    int pix = t & (HW - 1);
    float msum = 0.f, mmax = -INFINITY;
    for (int c = 0; c < 64; c++) {
        int g = c >> 2;
        float mean = stats[b * 16 + g];
        float rstd = stats[32 + b * 16 + g];
        size_t idx = ((size_t)b * 64 + c) * HW + pix;
        float v = (dc[idx] - mean) * rstd * gamma[c] + beta[c];
        v = fmaxf(v, 0.f);
        c1[idx] = v;
        msum += v;
        mmax = fmaxf(mmax, v);
    }
    cm[t] = msum * (1.0f / 64.0f);
    cx[t] = mmax;
}

// ---------------------------------------------------------------------------
// Kernel 5: spatial-attention 1-ch 3x3 convs + sigmoid, scale & concat.
// cat[b][0:64]   = sigmoid(conv(cm)) * c1
// cat[b][64:128] = sigmoid(conv(cx)) * c1
// ---------------------------------------------------------------------------
__global__ __launch_bounds__(256) void attn_cat(
    const float* __restrict__ c1, const float* __restrict__ cm,
    const float* __restrict__ cx,
    const float* __restrict__ wa, const float* __restrict__ ba,
    const float* __restrict__ wb, const float* __restrict__ bb,
    float* __restrict__ cat)
{
    int t = blockIdx.x * 256 + threadIdx.x;
    if (t >= BATCH * HW) return;
    int b = t >> 14;
    int pix = t & (HW - 1);
    int i = pix >> 7, j = pix & (W - 1);
    float sa = ba[0], sb = bb[0];
    #pragma unroll
    for (int di = 0; di < 3; di++) {
        int ii = i + di - 1;
        if (ii < 0 || ii >= H) continue;
        #pragma unroll
        for (int dj = 0; dj < 3; dj++) {
            int jj = j + dj - 1;
            if (jj < 0 || jj >= W) continue;
            int q = (b << 14) + (ii << 7) + jj;
            sa = fmaf(cm[q], wa[di * 3 + dj], sa);
            sb = fmaf(cx[q], wb[di * 3 + dj], sb);
        }
    }
    float av = sigmoidf_(sa);
    float mv = sigmoidf_(sb);
    for (int c = 0; c < 64; c++) {
        float v = c1[((size_t)b * 64 + c) * HW + pix];
        cat[((size_t)b * 128 + c) * HW + pix]      = av * v;
        cat[((size_t)b * 128 + 64 + c) * HW + pix] = mv * v;
    }
}

// ---------------------------------------------------------------------------
// Kernel 9: final GN + relu -> d_out (elementwise)
// ---------------------------------------------------------------------------
__global__ __launch_bounds__(256) void gn_final(
    const float* __restrict__ dc, const float* __restrict__ stats,
    const float* __restrict__ gamma, const float* __restrict__ beta,
    float* __restrict__ out)
{
    int t = blockIdx.x * 256 + threadIdx.x;
    if (t >= BATCH * 64 * HW) return;
    int c = (t >> 14) & 63;
    int b = t >> 20;
    int g = c >> 2;
    float mean = stats[b * 16 + g];
    float rstd = stats[32 + b * 16 + g];
    float v = (dc[t] - mean) * rstd * gamma[c] + beta[c];
    out[t] = fmaxf(v, 0.f);
}

// ---------------------------------------------------------------------------
extern "C" void kernel_launch(void* const* d_in, const int* in_sizes, int n_in,
                              void* d_out, int out_size, void* d_ws, size_t ws_size,
                              hipStream_t stream) {
    (void)in_sizes; (void)n_in; (void)out_size; (void)ws_size;
    const float* x   = (const float*)d_in[0];
    const float* wp1 = (const float*)d_in[1];
    const float* bp1 = (const float*)d_in[2];
    const float* wm1 = (const float*)d_in[3];
    const float* bm1 = (const float*)d_in[4];
    const float* wc1 = (const float*)d_in[5];
    const float* g1  = (const float*)d_in[6];
    const float* be1 = (const float*)d_in[7];
    const float* wa  = (const float*)d_in[8];
    const float* ba  = (const float*)d_in[9];
    const float* wb  = (const float*)d_in[10];
    const float* bb  = (const float*)d_in[11];
    const float* wp2 = (const float*)d_in[12];
    const float* bp2 = (const float*)d_in[13];
    const float* wm2 = (const float*)d_in[14];
    const float* bm2 = (const float*)d_in[15];
    const float* wc2 = (const float*)d_in[16];
    const float* g2  = (const float*)d_in[17];
    const float* be2 = (const float*)d_in[18];
    float* out = (float*)d_out;

    // workspace layout (floats), buffers reused between the two stages
    float* ws   = (float*)d_ws;
    float* offb = ws;                          // 2*27*HW   = 884736
    float* dcb  = offb + 2 * 27 * HW;          // 2*64*HW   = 2097152
    float* c1b  = dcb + 2 * 64 * HW;           // 2*64*HW   = 2097152
    float* cmb  = c1b + 2 * 64 * HW;           // 2*HW      = 32768
    float* cxb  = cmb + 2 * HW;                // 2*HW      = 32768
    float* catb = cxb + 2 * HW;                // 2*128*HW  = 4194304
    float* stb  = catb + 2 * 128 * HW;         // 64

    const int NOFF = (BATCH * HW * 9 + 255) / 256;   // 1152 blocks
    const int NPIXB = (BATCH * HW + 255) / 256;      // 128 blocks
    const int NDEF = BATCH * HW / 8;                 // 4096 blocks

    // ---- stage 1 ----
    conv_offmask<64><<<NOFF, 256, 0, stream>>>(x, wp1, bp1, wm1, bm1, offb);
    deform_conv<64><<<NDEF, 256, 0, stream>>>(x, offb, wc1, dcb);
    gn_stats<<<32, 256, 0, stream>>>(dcb, stb);
    gn_apply_meanmax<<<NPIXB, 256, 0, stream>>>(dcb, stb, g1, be1, c1b, cmb, cxb);
    attn_cat<<<NPIXB, 256, 0, stream>>>(c1b, cmb, cxb, wa, ba, wb, bb, catb);

    // ---- stage 2 ----
    conv_offmask<128><<<NOFF, 256, 0, stream>>>(catb, wp2, bp2, wm2, bm2, offb);
    deform_conv<128><<<NDEF, 256, 0, stream>>>(catb, offb, wc2, dcb);
    gn_stats<<<32, 256, 0, stream>>>(dcb, stb);
    gn_final<<<(BATCH * 64 * HW + 255) / 256, 256, 0, stream>>>(dcb, stb, g2, be2, out);
}

// Round 2
// 860.724 us; speedup vs baseline: 1.3313x; 1.3313x over previous
//
#include <hip/hip_runtime.h>
#include <math.h>

#define H 128
#define W 128
#define HW (H*W)
#define BATCH 2

__device__ __forceinline__ float sigmoidf_(float x){ return 1.0f/(1.0f + expf(-x)); }

// ---------------------------------------------------------------------------
// Weight transpose: w [64][K] -> wt [K][64]  (runs once per call, tiny)
// ---------------------------------------------------------------------------
__global__ __launch_bounds__(256) void transpose_w(
    const float* __restrict__ w, float* __restrict__ wt, int K)
{
    int t = blockIdx.x * 256 + threadIdx.x;
    if (t >= 64 * K) return;
    int oc = t / K, k = t - oc * K;
    wt[k * 64 + oc] = w[t];
}

// ---------------------------------------------------------------------------
// Kernel 1/6: 3x3 conv (pad 1) producing 18 offset channels + 9 sigmoid(mask)
// channels. out layout: [B][27][HW]  (0..17 offsets, 18..26 mask)
// ---------------------------------------------------------------------------
template<int CIN>
__global__ __launch_bounds__(256) void conv_offmask(
    const float* __restrict__ x,    // [B][CIN][HW]
    const float* __restrict__ wp,   // [18][CIN][3][3]
    const float* __restrict__ bp,   // [18]
    const float* __restrict__ wm,   // [9][CIN][3][3]
    const float* __restrict__ bm,   // [9]
    float* __restrict__ out)        // [B][27][HW]
{
    int t = blockIdx.x * 256 + threadIdx.x;
    if (t >= BATCH * HW * 9) return;
    int g   = t / (BATCH * HW);
    int r   = t - g * (BATCH * HW);
    int b   = r >> 14;
    int pix = r & (HW - 1);
    int i = pix >> 7, j = pix & (W - 1);

    bool ismask = (g >= 6);
    const float* wbase = ismask ? (wm + (size_t)(g - 6) * 3 * CIN * 9)
                                : (wp + (size_t)g * 3 * CIN * 9);
    float a0 = 0.f, a1 = 0.f, a2 = 0.f;
    const float* xb = x + (size_t)b * CIN * HW;
    for (int c = 0; c < CIN; c++) {
        const float* xp = xb + (size_t)c * HW;
        const float* wc = wbase + c * 9;
        #pragma unroll
        for (int di = 0; di < 3; di++) {
            int ii = i + di - 1;
            if (ii < 0 || ii >= H) continue;
            #pragma unroll
            for (int dj = 0; dj < 3; dj++) {
                int jj = j + dj - 1;
                if (jj < 0 || jj >= W) continue;
                float xv = xp[ii * W + jj];
                int wi = di * 3 + dj;
                a0 = fmaf(xv, wc[wi], a0);
                a1 = fmaf(xv, wc[CIN * 9 + wi], a1);
                a2 = fmaf(xv, wc[2 * CIN * 9 + wi], a2);
            }
        }
    }
    int oc;
    if (ismask) {
        int o0 = (g - 6) * 3;
        a0 = sigmoidf_(a0 + bm[o0]);
        a1 = sigmoidf_(a1 + bm[o0 + 1]);
        a2 = sigmoidf_(a2 + bm[o0 + 2]);
        oc = 18 + o0;
    } else {
        int o0 = g * 3;
        a0 += bp[o0]; a1 += bp[o0 + 1]; a2 += bp[o0 + 2];
        oc = o0;
    }
    float* ob = out + ((size_t)b * 27 + oc) * HW + pix;
    ob[0] = a0; ob[HW] = a1; ob[2 * HW] = a2;
}

// ---------------------------------------------------------------------------
// Deformable sampling + main conv as register-blocked matmul.
// Tile: 64 oc x 32 pix, K-chunk = 36 (4 channels x 9 taps).
// 256 threads. Matmul role: to=tid&15 (4 oc), tp=tid>>4 (2 pix) -> acc[4][2].
// Sampling role: sp=tid>>3 (pixel), sc=(tid>>1)&3 (channel-in-chunk),
//                shalf=tid&1 (n in {half*5..}). Bilinear meta in REGISTERS.
// Weights pre-transposed wT[K][64] -> coalesced stage, conflict-free reads.
// ---------------------------------------------------------------------------
template<int CIN>
__global__ __launch_bounds__(256) void deform_conv2(
    const float* __restrict__ src,   // [B][CIN][HW]
    const float* __restrict__ off,   // [B][27][HW]
    const float* __restrict__ wT,    // [CIN*9][64]
    float* __restrict__ out)         // [B][64][HW]
{
    constexpr int K   = CIN * 9;
    constexpr int KC  = 36;
    constexpr int NCH = K / KC;          // 16 or 32 chunks
    __shared__ __align__(16) float wl[KC][64];
    __shared__ __align__(16) float sb[KC][40];   // pad to 40 floats/row

    int tid  = threadIdx.x;
    int pix0 = blockIdx.x * 32;
    int b    = pix0 >> 14;
    int base = pix0 & (HW - 1);
    int i    = base >> 7;
    int j0   = base & (W - 1);

    // ---- sampling-role constants + per-thread bilinear meta (registers) ----
    int sp    = tid >> 3;          // 0..31 pixel within tile
    int sc    = (tid >> 1) & 3;    // 0..3 channel within chunk
    int shalf = tid & 1;           // n range: half0 -> 0..4, half1 -> 5..8
    int   midx[5][4];
    float mwt [5][4];
    {
        int j = j0 + sp;
        int pix = (i << 7) + j;
        const float* ob = off + (size_t)b * 27 * HW + pix;
        #pragma unroll
        for (int r = 0; r < 5; r++) {
            int n = shalf * 5 + r;
            if (n < 9) {
                float px = ob[(size_t)n * HW]       + (float)(n / 3 - 1) + (float)(i + 1);
                float py = ob[(size_t)(9 + n) * HW] + (float)(n % 3 - 1) + (float)(j + 1);
                float mk = ob[(size_t)(18 + n) * HW];
                float fx = floorf(px), fy = floorf(py);
                const float lim = 129.0f;           // Hp-1 = Wp-1
                int qltx = (int)fminf(fmaxf(fx, 0.f), lim);
                int qlty = (int)fminf(fmaxf(fy, 0.f), lim);
                int qrbx = (int)fminf(fmaxf(fx + 1.f, 0.f), lim);
                int qrby = (int)fminf(fmaxf(fy + 1.f, 0.f), lim);
                float pxc = fminf(fmaxf(px, 0.f), lim);
                float pyc = fminf(fmaxf(py, 0.f), lim);
                float gxl = 1.f + ((float)qltx - pxc);
                float gxr = 1.f - ((float)qrbx - pxc);
                float gyl = 1.f + ((float)qlty - pyc);
                float gyr = 1.f - ((float)qrby - pyc);
                int   xs[4] = {qltx, qrbx, qltx, qrbx};
                int   ys[4] = {qlty, qrby, qrby, qlty};
                float gs[4] = {gxl * gyl, gxr * gyr, gxl * gyr, gxr * gyl};
                #pragma unroll
                for (int q = 0; q < 4; q++) {
                    int qx = xs[q], qy = ys[q];
                    bool valid = (qx >= 1 && qx <= H && qy >= 1 && qy <= W);
                    midx[r][q] = valid ? ((qx - 1) * W + (qy - 1)) : -1;
                    mwt[r][q]  = gs[q] * mk;
                }
            }
        }
    }

    // ---- matmul-role constants ----
    int to = tid & 15;     // oc group: oc = to*4 .. to*4+3
    int tp = tid >> 4;     // pix group: pix = base + tp*2 .. +1
    float acc[4][2] = {{0.f,0.f},{0.f,0.f},{0.f,0.f},{0.f,0.f}};

    const float* srcb = src + (size_t)b * CIN * HW;

    for (int ch = 0; ch < NCH; ch++) {
        int kk = ch * KC;
        // stage weight chunk (coalesced read, sequential LDS write)
        #pragma unroll
        for (int r = 0; r < 9; r++) {
            int idx = r * 256 + tid;
            int kp = idx >> 6, oc = idx & 63;
            wl[kp][oc] = wT[(size_t)(kk + kp) * 64 + oc];
        }
        // sample chunk: this thread covers (sp, c0+sc, n in its half)
        const float* plane = srcb + (size_t)(ch * 4 + sc) * HW;
        #pragma unroll
        for (int r = 0; r < 5; r++) {
            int n = shalf * 5 + r;
            if (n < 9) {
                float v = 0.f;
                #pragma unroll
                for (int q = 0; q < 4; q++) {
                    int ix = midx[r][q];
                    float xv = (ix >= 0) ? plane[ix] : 0.f;
                    v = fmaf(xv, mwt[r][q], v);
                }
                sb[sc * 9 + n][sp] = v;
            }
        }
        __syncthreads();
        // matmul: 36 k, 8 FMA each
        #pragma unroll
        for (int kq = 0; kq < KC; kq++) {
            float4 w4 = *reinterpret_cast<const float4*>(&wl[kq][to << 2]);
            float2 s2 = *reinterpret_cast<const float2*>(&sb[kq][tp << 1]);
            acc[0][0] = fmaf(w4.x, s2.x, acc[0][0]);
            acc[0][1] = fmaf(w4.x, s2.y, acc[0][1]);
            acc[1][0] = fmaf(w4.y, s2.x, acc[1][0]);
            acc[1][1] = fmaf(w4.y, s2.y, acc[1][1]);
            acc[2][0] = fmaf(w4.z, s2.x, acc[2][0]);
            acc[2][1] = fmaf(w4.z, s2.y, acc[2][1]);
            acc[3][0] = fmaf(w4.w, s2.x, acc[3][0]);
            acc[3][1] = fmaf(w4.w, s2.y, acc[3][1]);
        }
        __syncthreads();
    }

    // ---- store: 4 oc x 2 consecutive pixels each ----
    #pragma unroll
    for (int s = 0; s < 4; s++) {
        float2 v = make_float2(acc[s][0], acc[s][1]);
        *reinterpret_cast<float2*>(
            out + ((size_t)b * 64 + (to << 2) + s) * HW + base + (tp << 1)) = v;
    }
}

// ---------------------------------------------------------------------------
// Group-norm statistics. One block per (b, group); 4 consecutive channels.
// stats[bg] = mean, stats[32+bg] = rstd
// ---------------------------------------------------------------------------
__global__ __launch_bounds__(256) void gn_stats(
    const float* __restrict__ buf, float* __restrict__ stats)
{
    int bg = blockIdx.x;                       // 0..31
    const float4* v = reinterpret_cast<const float4*>(buf + (size_t)bg * 4 * HW);
    float sum = 0.f, ssq = 0.f;
    for (int idx = threadIdx.x; idx < 4 * HW / 4; idx += 256) {
        float4 x = v[idx];
        sum += x.x + x.y + x.z + x.w;
        ssq += x.x * x.x + x.y * x.y + x.z * x.z + x.w * x.w;
    }
    #pragma unroll
    for (int d = 32; d > 0; d >>= 1) {
        sum += __shfl_down(sum, d);
        ssq += __shfl_down(ssq, d);
    }
    __shared__ float ws1[4], ws2[4];
    int wid = threadIdx.x >> 6;
    if ((threadIdx.x & 63) == 0) { ws1[wid] = sum; ws2[wid] = ssq; }
    __syncthreads();
    if (threadIdx.x == 0) {
        float S = ws1[0] + ws1[1] + ws1[2] + ws1[3];
        float Q = ws2[0] + ws2[1] + ws2[2] + ws2[3];
        float mean = S * (1.0f / (4.0f * HW));
        float var  = Q * (1.0f / (4.0f * HW)) - mean * mean;
        stats[bg]      = mean;
        stats[32 + bg] = rsqrtf(var + 1e-5f);
    }
}

// ---------------------------------------------------------------------------
// Apply GN+relu -> c1, and produce channel mean & max maps.
// ---------------------------------------------------------------------------
__global__ __launch_bounds__(256) void gn_apply_meanmax(
    const float* __restrict__ dc, const float* __restrict__ stats,
    const float* __restrict__ gamma, const float* __restrict__ beta,
    float* __restrict__ c1, float* __restrict__ cm, float* __restrict__ cx)
{
    int t = blockIdx.x * 256 + threadIdx.x;
    if (t >= BATCH * HW) return;
    int b = t >> 14;
    int pix = t & (HW - 1);
    float msum = 0.f, mmax = -INFINITY;
    for (int c = 0; c < 64; c++) {
        int g = c >> 2;
        float mean = stats[b * 16 + g];
        float rstd = stats[32 + b * 16 + g];
        size_t idx = ((size_t)b * 64 + c) * HW + pix;
        float v = (dc[idx] - mean) * rstd * gamma[c] + beta[c];
        v = fmaxf(v, 0.f);
        c1[idx] = v;
        msum += v;
        mmax = fmaxf(mmax, v);
    }
    cm[t] = msum * (1.0f / 64.0f);
    cx[t] = mmax;
}

// ---------------------------------------------------------------------------
// Spatial-attention 1-ch 3x3 convs + sigmoid, scale & concat.
// ---------------------------------------------------------------------------
__global__ __launch_bounds__(256) void attn_cat(
    const float* __restrict__ c1, const float* __restrict__ cm,
    const float* __restrict__ cx,
    const float* __restrict__ wa, const float* __restrict__ ba,
    const float* __restrict__ wb, const float* __restrict__ bb,
    float* __restrict__ cat)
{
    int t = blockIdx.x * 256 + threadIdx.x;
    if (t >= BATCH * HW) return;
    int b = t >> 14;
    int pix = t & (HW - 1);
    int i = pix >> 7, j = pix & (W - 1);
    float sa = ba[0], sb = bb[0];
    #pragma unroll
    for (int di = 0; di < 3; di++) {
        int ii = i + di - 1;
        if (ii < 0 || ii >= H) continue;
        #pragma unroll
        for (int dj = 0; dj < 3; dj++) {
            int jj = j + dj - 1;
            if (jj < 0 || jj >= W) continue;
            int q = (b << 14) + (ii << 7) + jj;
            sa = fmaf(cm[q], wa[di * 3 + dj], sa);
            sb = fmaf(cx[q], wb[di * 3 + dj], sb);
        }
    }
    float av = sigmoidf_(sa);
    float mv = sigmoidf_(sb);
    for (int c = 0; c < 64; c++) {
        float v = c1[((size_t)b * 64 + c) * HW + pix];
        cat[((size_t)b * 128 + c) * HW + pix]      = av * v;
        cat[((size_t)b * 128 + 64 + c) * HW + pix] = mv * v;
    }
}

// ---------------------------------------------------------------------------
// Final GN + relu -> d_out (elementwise)
// ---------------------------------------------------------------------------
__global__ __launch_bounds__(256) void gn_final(
    const float* __restrict__ dc, const float* __restrict__ stats,
    const float* __restrict__ gamma, const float* __restrict__ beta,
    float* __restrict__ out)
{
    int t = blockIdx.x * 256 + threadIdx.x;
    if (t >= BATCH * 64 * HW) return;
    int c = (t >> 14) & 63;
    int b = t >> 20;
    int g = c >> 2;
    float mean = stats[b * 16 + g];
    float rstd = stats[32 + b * 16 + g];
    float v = (dc[t] - mean) * rstd * gamma[c] + beta[c];
    out[t] = fmaxf(v, 0.f);
}

// ---------------------------------------------------------------------------
extern "C" void kernel_launch(void* const* d_in, const int* in_sizes, int n_in,
                              void* d_out, int out_size, void* d_ws, size_t ws_size,
                              hipStream_t stream) {
    (void)in_sizes; (void)n_in; (void)out_size; (void)ws_size;
    const float* x   = (const float*)d_in[0];
    const float* wp1 = (const float*)d_in[1];
    const float* bp1 = (const float*)d_in[2];
    const float* wm1 = (const float*)d_in[3];
    const float* bm1 = (const float*)d_in[4];
    const float* wc1 = (const float*)d_in[5];
    const float* g1  = (const float*)d_in[6];
    const float* be1 = (const float*)d_in[7];
    const float* wa  = (const float*)d_in[8];
    const float* ba  = (const float*)d_in[9];
    const float* wb  = (const float*)d_in[10];
    const float* bb  = (const float*)d_in[11];
    const float* wp2 = (const float*)d_in[12];
    const float* bp2 = (const float*)d_in[13];
    const float* wm2 = (const float*)d_in[14];
    const float* bm2 = (const float*)d_in[15];
    const float* wc2 = (const float*)d_in[16];
    const float* g2  = (const float*)d_in[17];
    const float* be2 = (const float*)d_in[18];
    float* out = (float*)d_out;

    // workspace layout (floats)
    float* ws   = (float*)d_ws;
    float* offb = ws;                          // 2*27*HW
    float* dcb  = offb + 2 * 27 * HW;          // 2*64*HW
    float* c1b  = dcb + 2 * 64 * HW;           // 2*64*HW
    float* cmb  = c1b + 2 * 64 * HW;           // 2*HW
    float* cxb  = cmb + 2 * HW;                // 2*HW
    float* catb = cxb + 2 * HW;                // 2*128*HW
    float* stb  = catb + 2 * 128 * HW;         // 64

    // transposed weights live in d_out scratch (fully rewritten by gn_final)
    float* wt1 = out;                          // 576*64  = 36864
    float* wt2 = out + 576 * 64;               // 1152*64 = 73728  (fits: out 2M)

    const int NOFF  = (BATCH * HW * 9 + 255) / 256;
    const int NPIXB = (BATCH * HW + 255) / 256;
    const int NDEF  = BATCH * HW / 32;               // 1024 blocks

    transpose_w<<<(64 * 576 + 255) / 256, 256, 0, stream>>>(wc1, wt1, 576);
    transpose_w<<<(64 * 1152 + 255) / 256, 256, 0, stream>>>(wc2, wt2, 1152);

    // ---- stage 1 ----
    conv_offmask<64><<<NOFF, 256, 0, stream>>>(x, wp1, bp1, wm1, bm1, offb);
    deform_conv2<64><<<NDEF, 256, 0, stream>>>(x, offb, wt1, dcb);
    gn_stats<<<32, 256, 0, stream>>>(dcb, stb);
    gn_apply_meanmax<<<NPIXB, 256, 0, stream>>>(dcb, stb, g1, be1, c1b, cmb, cxb);
    attn_cat<<<NPIXB, 256, 0, stream>>>(c1b, cmb, cxb, wa, ba, wb, bb, catb);

    // ---- stage 2 ----
    conv_offmask<128><<<NOFF, 256, 0, stream>>>(catb, wp2, bp2, wm2, bm2, offb);
    deform_conv2<128><<<NDEF, 256, 0, stream>>>(catb, offb, wt2, dcb);
    gn_stats<<<32, 256, 0, stream>>>(dcb, stb);
    gn_final<<<(BATCH * 64 * HW + 255) / 256, 256, 0, stream>>>(dcb, stb, g2, be2, out);
}

// Round 3
// 520.431 us; speedup vs baseline: 2.2018x; 1.6539x over previous
//
#include <hip/hip_runtime.h>
#include <math.h>

#define H 128
#define W 128
#define HW (H*W)
#define BATCH 2

__device__ __forceinline__ float sigmoidf_(float x){ return 1.0f/(1.0f + expf(-x)); }

// ---------------------------------------------------------------------------
// Weight transpose for deform conv: w [64][K] -> wt [K][64]
// ---------------------------------------------------------------------------
__global__ __launch_bounds__(256) void transpose_w(
    const float* __restrict__ w, float* __restrict__ wt, int K)
{
    int t = blockIdx.x * 256 + threadIdx.x;
    if (t >= 64 * K) return;
    int oc = t / K, k = t - oc * K;
    wt[k * 64 + oc] = w[t];
}

// ---------------------------------------------------------------------------
// Weight transpose for offset/mask conv:
// wp [18][CIN][9], wm [9][CIN][9] -> wt [(c*9+n)*32 + oc], oc 0..26
// ---------------------------------------------------------------------------
template<int CIN>
__global__ __launch_bounds__(256) void transpose_woff(
    const float* __restrict__ wp, const float* __restrict__ wm,
    float* __restrict__ wt)
{
    int t = blockIdx.x * 256 + threadIdx.x;
    if (t >= 27 * CIN * 9) return;
    int oc  = t / (CIN * 9);
    int rem = t - oc * (CIN * 9);
    int c = rem / 9, n = rem - (rem / 9) * 9;
    float v = (oc < 18) ? wp[((size_t)oc * CIN + c) * 9 + n]
                        : wm[((size_t)(oc - 18) * CIN + c) * 9 + n];
    wt[(size_t)(c * 9 + n) * 32 + oc] = v;
}

// ---------------------------------------------------------------------------
// Offset/mask 3x3 conv, GEMM-style: each thread owns ONE pixel and computes
// all 27 output channels over a 1/4 slice of input channels (channel-split
// for occupancy). Weights are read via thread-uniform addresses -> SGPRs.
// part layout: [split][B][27][HW]
// ---------------------------------------------------------------------------
template<int CIN>
__global__ __launch_bounds__(256) void conv_off_part(
    const float* __restrict__ x,    // [B][CIN][HW]
    const float* __restrict__ wt,   // [(c*9+n)*32 + oc]
    float* __restrict__ part)       // [4][B][27][HW]
{
    constexpr int CPS = CIN / 4;
    int bid   = blockIdx.x;
    int split = bid & 3;
    int tile  = bid >> 2;
    int t   = tile * 256 + threadIdx.x;    // 0 .. B*HW-1
    int b   = t >> 14;
    int pix = t & (HW - 1);
    int i = pix >> 7, j = pix & (W - 1);

    int   off9[9];
    float msk [9];
    #pragma unroll
    for (int r = 0; r < 9; r++) {
        int ii = i + r / 3 - 1;
        int jj = j + r % 3 - 1;
        bool v = (ii >= 0 && ii < H && jj >= 0 && jj < W);
        off9[r] = v ? (ii * W + jj) : 0;
        msk[r]  = v ? 1.f : 0.f;
    }

    float acc[27];
    #pragma unroll
    for (int o = 0; o < 27; o++) acc[o] = 0.f;

    const float* xb = x  + ((size_t)b * CIN + split * CPS) * HW;
    const float* wb = wt + (size_t)split * CPS * 9 * 32;

    for (int c = 0; c < CPS; c++) {
        float nb[9];
        #pragma unroll
        for (int r = 0; r < 9; r++) nb[r] = xb[off9[r]] * msk[r];
        #pragma unroll
        for (int n = 0; n < 9; n++) {
            const float* wcn = wb + n * 32;   // thread-uniform -> s_load
            #pragma unroll
            for (int o = 0; o < 27; o++)
                acc[o] = fmaf(wcn[o], nb[n], acc[o]);
        }
        xb += HW;
        wb += 9 * 32;
    }

    float* pb = part + (((size_t)split * BATCH + b) * 27) * HW + pix;
    #pragma unroll
    for (int o = 0; o < 27; o++) pb[(size_t)o * HW] = acc[o];
}

// ---------------------------------------------------------------------------
// Reduce the 4 channel-split partials, add bias, sigmoid the mask channels.
// out layout: [B][27][HW]  (0..17 offsets, 18..26 mask)
// ---------------------------------------------------------------------------
__global__ __launch_bounds__(256) void conv_off_reduce(
    const float* __restrict__ part, const float* __restrict__ bp,
    const float* __restrict__ bm, float* __restrict__ out)
{
    int t4 = blockIdx.x * 256 + threadIdx.x;      // over B*27*HW/4
    if (t4 >= BATCH * 27 * HW / 4) return;
    int t   = t4 * 4;
    int b   = t / (27 * HW);
    int rem = t - b * 27 * HW;
    int oc  = rem / HW;
    int pix = rem - oc * HW;

    float4 s = make_float4(0.f, 0.f, 0.f, 0.f);
    #pragma unroll
    for (int sp = 0; sp < 4; sp++) {
        float4 v = *reinterpret_cast<const float4*>(
            part + (((size_t)sp * BATCH + b) * 27 + oc) * HW + pix);
        s.x += v.x; s.y += v.y; s.z += v.z; s.w += v.w;
    }
    if (oc < 18) {
        float bv = bp[oc];
        s.x += bv; s.y += bv; s.z += bv; s.w += bv;
    } else {
        float bv = bm[oc - 18];
        s.x = sigmoidf_(s.x + bv); s.y = sigmoidf_(s.y + bv);
        s.z = sigmoidf_(s.z + bv); s.w = sigmoidf_(s.w + bv);
    }
    *reinterpret_cast<float4*>(out + ((size_t)b * 27 + oc) * HW + pix) = s;
}

// ---------------------------------------------------------------------------
// Deformable sampling + main conv as register-blocked matmul.
// Tile: 64 oc x 32 pix, K-chunk = 36 (4 channels x 9 taps).
// ---------------------------------------------------------------------------
template<int CIN>
__global__ __launch_bounds__(256) void deform_conv2(
    const float* __restrict__ src,   // [B][CIN][HW]
    const float* __restrict__ off,   // [B][27][HW]
    const float* __restrict__ wT,    // [CIN*9][64]
    float* __restrict__ out)         // [B][64][HW]
{
    constexpr int K   = CIN * 9;
    constexpr int KC  = 36;
    constexpr int NCH = K / KC;
    __shared__ __align__(16) float wl[KC][64];
    __shared__ __align__(16) float sb[KC][40];

    int tid  = threadIdx.x;
    int pix0 = blockIdx.x * 32;
    int b    = pix0 >> 14;
    int base = pix0 & (HW - 1);
    int i    = base >> 7;
    int j0   = base & (W - 1);

    int sp    = tid >> 3;
    int sc    = (tid >> 1) & 3;
    int shalf = tid & 1;
    int   midx[5][4];
    float mwt [5][4];
    {
        int j = j0 + sp;
        int pix = (i << 7) + j;
        const float* ob = off + (size_t)b * 27 * HW + pix;
        #pragma unroll
        for (int r = 0; r < 5; r++) {
            int n = shalf * 5 + r;
            if (n < 9) {
                float px = ob[(size_t)n * HW]       + (float)(n / 3 - 1) + (float)(i + 1);
                float py = ob[(size_t)(9 + n) * HW] + (float)(n % 3 - 1) + (float)(j + 1);
                float mk = ob[(size_t)(18 + n) * HW];
                float fx = floorf(px), fy = floorf(py);
                const float lim = 129.0f;
                int qltx = (int)fminf(fmaxf(fx, 0.f), lim);
                int qlty = (int)fminf(fmaxf(fy, 0.f), lim);
                int qrbx = (int)fminf(fmaxf(fx + 1.f, 0.f), lim);
                int qrby = (int)fminf(fmaxf(fy + 1.f, 0.f), lim);
                float pxc = fminf(fmaxf(px, 0.f), lim);
                float pyc = fminf(fmaxf(py, 0.f), lim);
                float gxl = 1.f + ((float)qltx - pxc);
                float gxr = 1.f - ((float)qrbx - pxc);
                float gyl = 1.f + ((float)qlty - pyc);
                float gyr = 1.f - ((float)qrby - pyc);
                int   xs[4] = {qltx, qrbx, qltx, qrbx};
                int   ys[4] = {qlty, qrby, qrby, qlty};
                float gs[4] = {gxl * gyl, gxr * gyr, gxl * gyr, gxr * gyl};
                #pragma unroll
                for (int q = 0; q < 4; q++) {
                    int qx = xs[q], qy = ys[q];
                    bool valid = (qx >= 1 && qx <= H && qy >= 1 && qy <= W);
                    midx[r][q] = valid ? ((qx - 1) * W + (qy - 1)) : -1;
                    mwt[r][q]  = gs[q] * mk;
                }
            }
        }
    }

    int to = tid & 15;
    int tp = tid >> 4;
    float acc[4][2] = {{0.f,0.f},{0.f,0.f},{0.f,0.f},{0.f,0.f}};

    const float* srcb = src + (size_t)b * CIN * HW;

    for (int ch = 0; ch < NCH; ch++) {
        int kk = ch * KC;
        #pragma unroll
        for (int r = 0; r < 9; r++) {
            int idx = r * 256 + tid;
            int kp = idx >> 6, oc = idx & 63;
            wl[kp][oc] = wT[(size_t)(kk + kp) * 64 + oc];
        }
        const float* plane = srcb + (size_t)(ch * 4 + sc) * HW;
        #pragma unroll
        for (int r = 0; r < 5; r++) {
            int n = shalf * 5 + r;
            if (n < 9) {
                float v = 0.f;
                #pragma unroll
                for (int q = 0; q < 4; q++) {
                    int ix = midx[r][q];
                    float xv = (ix >= 0) ? plane[ix] : 0.f;
                    v = fmaf(xv, mwt[r][q], v);
                }
                sb[sc * 9 + n][sp] = v;
            }
        }
        __syncthreads();
        #pragma unroll
        for (int kq = 0; kq < KC; kq++) {
            float4 w4 = *reinterpret_cast<const float4*>(&wl[kq][to << 2]);
            float2 s2 = *reinterpret_cast<const float2*>(&sb[kq][tp << 1]);
            acc[0][0] = fmaf(w4.x, s2.x, acc[0][0]);
            acc[0][1] = fmaf(w4.x, s2.y, acc[0][1]);
            acc[1][0] = fmaf(w4.y, s2.x, acc[1][0]);
            acc[1][1] = fmaf(w4.y, s2.y, acc[1][1]);
            acc[2][0] = fmaf(w4.z, s2.x, acc[2][0]);
            acc[2][1] = fmaf(w4.z, s2.y, acc[2][1]);
            acc[3][0] = fmaf(w4.w, s2.x, acc[3][0]);
            acc[3][1] = fmaf(w4.w, s2.y, acc[3][1]);
        }
        __syncthreads();
    }

    #pragma unroll
    for (int s = 0; s < 4; s++) {
        float2 v = make_float2(acc[s][0], acc[s][1]);
        *reinterpret_cast<float2*>(
            out + ((size_t)b * 64 + (to << 2) + s) * HW + base + (tp << 1)) = v;
    }
}

// ---------------------------------------------------------------------------
// Group-norm statistics. One block per (b, group); 4 consecutive channels.
// ---------------------------------------------------------------------------
__global__ __launch_bounds__(256) void gn_stats(
    const float* __restrict__ buf, float* __restrict__ stats)
{
    int bg = blockIdx.x;
    const float4* v = reinterpret_cast<const float4*>(buf + (size_t)bg * 4 * HW);
    float sum = 0.f, ssq = 0.f;
    for (int idx = threadIdx.x; idx < 4 * HW / 4; idx += 256) {
        float4 x = v[idx];
        sum += x.x + x.y + x.z + x.w;
        ssq += x.x * x.x + x.y * x.y + x.z * x.z + x.w * x.w;
    }
    #pragma unroll
    for (int d = 32; d > 0; d >>= 1) {
        sum += __shfl_down(sum, d);
        ssq += __shfl_down(ssq, d);
    }
    __shared__ float ws1[4], ws2[4];
    int wid = threadIdx.x >> 6;
    if ((threadIdx.x & 63) == 0) { ws1[wid] = sum; ws2[wid] = ssq; }
    __syncthreads();
    if (threadIdx.x == 0) {
        float S = ws1[0] + ws1[1] + ws1[2] + ws1[3];
        float Q = ws2[0] + ws2[1] + ws2[2] + ws2[3];
        float mean = S * (1.0f / (4.0f * HW));
        float var  = Q * (1.0f / (4.0f * HW)) - mean * mean;
        stats[bg]      = mean;
        stats[32 + bg] = rsqrtf(var + 1e-5f);
    }
}

// ---------------------------------------------------------------------------
// Apply GN+relu -> c1, and produce channel mean & max maps.
// ---------------------------------------------------------------------------
__global__ __launch_bounds__(256) void gn_apply_meanmax(
    const float* __restrict__ dc, const float* __restrict__ stats,
    const float* __restrict__ gamma, const float* __restrict__ beta,
    float* __restrict__ c1, float* __restrict__ cm, float* __restrict__ cx)
{
    int t = blockIdx.x * 256 + threadIdx.x;
    if (t >= BATCH * HW) return;
    int b = t >> 14;
    int pix = t & (HW - 1);
    float msum = 0.f, mmax = -INFINITY;
    for (int c = 0; c < 64; c++) {
        int g = c >> 2;
        float mean = stats[b * 16 + g];
        float rstd = stats[32 + b * 16 + g];
        size_t idx = ((size_t)b * 64 + c) * HW + pix;
        float v = (dc[idx] - mean) * rstd * gamma[c] + beta[c];
        v = fmaxf(v, 0.f);
        c1[idx] = v;
        msum += v;
        mmax = fmaxf(mmax, v);
    }
    cm[t] = msum * (1.0f / 64.0f);
    cx[t] = mmax;
}

// ---------------------------------------------------------------------------
// Spatial-attention 1-ch 3x3 convs + sigmoid, scale & concat.
// ---------------------------------------------------------------------------
__global__ __launch_bounds__(256) void attn_cat(
    const float* __restrict__ c1, const float* __restrict__ cm,
    const float* __restrict__ cx,
    const float* __restrict__ wa, const float* __restrict__ ba,
    const float* __restrict__ wb, const float* __restrict__ bb,
    float* __restrict__ cat)
{
    int t = blockIdx.x * 256 + threadIdx.x;
    if (t >= BATCH * HW) return;
    int b = t >> 14;
    int pix = t & (HW - 1);
    int i = pix >> 7, j = pix & (W - 1);
    float sa = ba[0], sb = bb[0];
    #pragma unroll
    for (int di = 0; di < 3; di++) {
        int ii = i + di - 1;
        if (ii < 0 || ii >= H) continue;
        #pragma unroll
        for (int dj = 0; dj < 3; dj++) {
            int jj = j + dj - 1;
            if (jj < 0 || jj >= W) continue;
            int q = (b << 14) + (ii << 7) + jj;
            sa = fmaf(cm[q], wa[di * 3 + dj], sa);
            sb = fmaf(cx[q], wb[di * 3 + dj], sb);
        }
    }
    float av = sigmoidf_(sa);
    float mv = sigmoidf_(sb);
    for (int c = 0; c < 64; c++) {
        float v = c1[((size_t)b * 64 + c) * HW + pix];
        cat[((size_t)b * 128 + c) * HW + pix]      = av * v;
        cat[((size_t)b * 128 + 64 + c) * HW + pix] = mv * v;
    }
}

// ---------------------------------------------------------------------------
// Final GN + relu -> d_out (elementwise)
// ---------------------------------------------------------------------------
__global__ __launch_bounds__(256) void gn_final(
    const float* __restrict__ dc, const float* __restrict__ stats,
    const float* __restrict__ gamma, const float* __restrict__ beta,
    float* __restrict__ out)
{
    int t = blockIdx.x * 256 + threadIdx.x;
    if (t >= BATCH * 64 * HW) return;
    int c = (t >> 14) & 63;
    int b = t >> 20;
    int g = c >> 2;
    float mean = stats[b * 16 + g];
    float rstd = stats[32 + b * 16 + g];
    float v = (dc[t] - mean) * rstd * gamma[c] + beta[c];
    out[t] = fmaxf(v, 0.f);
}

// ---------------------------------------------------------------------------
extern "C" void kernel_launch(void* const* d_in, const int* in_sizes, int n_in,
                              void* d_out, int out_size, void* d_ws, size_t ws_size,
                              hipStream_t stream) {
    (void)in_sizes; (void)n_in; (void)out_size; (void)ws_size;
    const float* x   = (const float*)d_in[0];
    const float* wp1 = (const float*)d_in[1];
    const float* bp1 = (const float*)d_in[2];
    const float* wm1 = (const float*)d_in[3];
    const float* bm1 = (const float*)d_in[4];
    const float* wc1 = (const float*)d_in[5];
    const float* g1  = (const float*)d_in[6];
    const float* be1 = (const float*)d_in[7];
    const float* wa  = (const float*)d_in[8];
    const float* ba  = (const float*)d_in[9];
    const float* wb  = (const float*)d_in[10];
    const float* bb  = (const float*)d_in[11];
    const float* wp2 = (const float*)d_in[12];
    const float* bp2 = (const float*)d_in[13];
    const float* wm2 = (const float*)d_in[14];
    const float* bm2 = (const float*)d_in[15];
    const float* wc2 = (const float*)d_in[16];
    const float* g2  = (const float*)d_in[17];
    const float* be2 = (const float*)d_in[18];
    float* out = (float*)d_out;

    // workspace layout (floats)
    float* ws   = (float*)d_ws;
    float* offb = ws;                          // 2*27*HW   =   884736
    float* dcb  = offb + 2 * 27 * HW;          // 2*64*HW   =  2097152
    float* c1b  = dcb + 2 * 64 * HW;           // 2*64*HW   =  2097152
    float* cmb  = c1b + 2 * 64 * HW;           // 2*HW
    float* cxb  = cmb + 2 * HW;                // 2*HW
    float* catb = cxb + 2 * HW;                // 2*128*HW
    float* stb  = catb + 2 * 128 * HW;         // 64
    // conv partials (4*2*27*HW = 3538944 floats) alias the dcb+c1b region:
    // written before deform_conv writes dcb, consumed by conv_off_reduce.
    float* partb = dcb;

    // weight scratch lives in d_out (fully rewritten by gn_final at the end)
    float* wt1  = out;                         // deform wT1: 576*64  = 36864
    float* wt2  = wt1 + 576 * 64;              // deform wT2: 1152*64 = 73728
    float* wo1  = wt2 + 1152 * 64;             // offs wt1: 64*9*32   = 18432
    float* wo2  = wo1 + 64 * 9 * 32;           // offs wt2: 128*9*32  = 36864

    const int NPIXB = (BATCH * HW + 255) / 256;      // 128
    const int NDEF  = BATCH * HW / 32;               // 1024
    const int NCONV = NPIXB * 4;                     // 512 (channel-split 4)
    const int NRED  = (BATCH * 27 * HW / 4 + 255) / 256;

    transpose_w<<<(64 * 576 + 255) / 256, 256, 0, stream>>>(wc1, wt1, 576);
    transpose_w<<<(64 * 1152 + 255) / 256, 256, 0, stream>>>(wc2, wt2, 1152);
    transpose_woff<64><<<(27 * 64 * 9 + 255) / 256, 256, 0, stream>>>(wp1, wm1, wo1);
    transpose_woff<128><<<(27 * 128 * 9 + 255) / 256, 256, 0, stream>>>(wp2, wm2, wo2);

    // ---- stage 1 ----
    conv_off_part<64><<<NCONV, 256, 0, stream>>>(x, wo1, partb);
    conv_off_reduce<<<NRED, 256, 0, stream>>>(partb, bp1, bm1, offb);
    deform_conv2<64><<<NDEF, 256, 0, stream>>>(x, offb, wt1, dcb);
    gn_stats<<<32, 256, 0, stream>>>(dcb, stb);
    gn_apply_meanmax<<<NPIXB, 256, 0, stream>>>(dcb, stb, g1, be1, c1b, cmb, cxb);
    attn_cat<<<NPIXB, 256, 0, stream>>>(c1b, cmb, cxb, wa, ba, wb, bb, catb);

    // ---- stage 2 ----
    conv_off_part<128><<<NCONV, 256, 0, stream>>>(catb, wo2, partb);
    conv_off_reduce<<<NRED, 256, 0, stream>>>(partb, bp2, bm2, offb);
    deform_conv2<128><<<NDEF, 256, 0, stream>>>(catb, offb, wt2, dcb);
    gn_stats<<<32, 256, 0, stream>>>(dcb, stb);
    gn_final<<<(BATCH * 64 * HW + 255) / 256, 256, 0, stream>>>(dcb, stb, g2, be2, out);
}

// Round 4
// 315.992 us; speedup vs baseline: 3.6262x; 1.6470x over previous
//
#include <hip/hip_runtime.h>
#include <math.h>

#define H 128
#define W 128
#define HW (H*W)
#define BATCH 2

typedef __attribute__((ext_vector_type(8))) short          bf16x8;
typedef __attribute__((ext_vector_type(4))) float          f32x4;
typedef __attribute__((ext_vector_type(8))) unsigned short u16x8;

__device__ __forceinline__ float sigmoidf_(float x){ return 1.0f/(1.0f + expf(-x)); }

// RTNE float -> bf16 bits
__device__ __forceinline__ unsigned short f2bf(float f) {
    unsigned u = __float_as_uint(f);
    u += 0x7FFFu + ((u >> 16) & 1u);
    return (unsigned short)(u >> 16);
}
__device__ __forceinline__ float bf2f(unsigned short b) {
    return __uint_as_float(((unsigned)b) << 16);
}

// ---------------------------------------------------------------------------
// Transpose x [B][64][HW] -> xt [B][HW][64]  (LDS-tiled, conflict-free)
// ---------------------------------------------------------------------------
__global__ __launch_bounds__(256) void transpose_x64(
    const float* __restrict__ x, float* __restrict__ xt)
{
    __shared__ float tile[64][65];
    int blk = blockIdx.x;               // 512 = 2 b * 256 pix-tiles
    int b  = blk >> 8;
    int p0 = (blk & 255) * 64;
    int tr = threadIdx.x >> 6;          // 0..3
    int tc = threadIdx.x & 63;          // 0..63
    #pragma unroll
    for (int r = 0; r < 16; r++) {
        int c = r * 4 + tr;
        tile[c][tc] = x[((size_t)b * 64 + c) * HW + p0 + tc];
    }
    __syncthreads();
    #pragma unroll
    for (int r = 0; r < 16; r++) {
        int p = r * 4 + tr;
        xt[((size_t)b * HW + p0 + p) * 64 + tc] = tile[tc][p];
    }
}

// ---------------------------------------------------------------------------
// Deform-conv weights: wc [64][CIN][9] fp32 -> wtp [64][NCH*96] bf16,
// k' = ch*96 + n*8 + cl  (n 0..8 real, 9..11 zero-pad; cl = channel-in-chunk)
// ---------------------------------------------------------------------------
template<int CIN>
__global__ __launch_bounds__(256) void transpose_wpad(
    const float* __restrict__ wc, unsigned short* __restrict__ wtp)
{
    constexpr int NCH = CIN / 8;
    int t = blockIdx.x * 256 + threadIdx.x;
    if (t >= 64 * NCH * 96) return;
    int oc = t / (NCH * 96);
    int r  = t - oc * (NCH * 96);
    int ch = r / 96;
    int q  = r - ch * 96;
    int n  = q >> 3, cl = q & 7;
    float v = (n < 9) ? wc[((size_t)oc * CIN + ch * 8 + cl) * 9 + n] : 0.f;
    wtp[t] = f2bf(v);
}

// ---------------------------------------------------------------------------
// Offset/mask conv weights: wp [18][CIN][9], wm [9][CIN][9]
//   -> wt [(c*9+n)*32 + oc], oc 0..26
// ---------------------------------------------------------------------------
template<int CIN>
__global__ __launch_bounds__(256) void transpose_woff(
    const float* __restrict__ wp, const float* __restrict__ wm,
    float* __restrict__ wt)
{
    int t = blockIdx.x * 256 + threadIdx.x;
    if (t >= 27 * CIN * 9) return;
    int oc  = t / (CIN * 9);
    int rem = t - oc * (CIN * 9);
    int c = rem / 9, n = rem - (rem / 9) * 9;
    float v = (oc < 18) ? wp[((size_t)oc * CIN + c) * 9 + n]
                        : wm[((size_t)(oc - 18) * CIN + c) * 9 + n];
    wt[(size_t)(c * 9 + n) * 32 + oc] = v;
}

// ---------------------------------------------------------------------------
// Offset/mask 3x3 conv from CHANNEL-MAJOR input xt [B][HW][CIN].
// Thread = one pixel, all 27 oc, over a 1/4 channel slice (split for occup.).
// part layout: [split][B][27][HW]
// ---------------------------------------------------------------------------
template<int CIN>
__global__ __launch_bounds__(256) void conv_off_part(
    const float* __restrict__ xt,   // [B][HW][CIN]
    const float* __restrict__ wt,   // [(c*9+n)*32 + oc]
    float* __restrict__ part)       // [4][B][27][HW]
{
    constexpr int CPS = CIN / 4;
    int bid   = blockIdx.x;
    int split = bid & 3;
    int tile  = bid >> 2;
    int t   = tile * 256 + threadIdx.x;
    int b   = t >> 14;
    int pix = t & (HW - 1);
    int i = pix >> 7, j = pix & (W - 1);

    const float* nbase[9];
    float msk[9];
    #pragma unroll
    for (int r = 0; r < 9; r++) {
        int ii = i + r / 3 - 1;
        int jj = j + r % 3 - 1;
        bool v = (ii >= 0 && ii < H && jj >= 0 && jj < W);
        nbase[r] = xt + ((size_t)b * HW + (v ? (ii * W + jj) : 0)) * CIN;
        msk[r]   = v ? 1.f : 0.f;
    }

    float acc[27];
    #pragma unroll
    for (int o = 0; o < 27; o++) acc[o] = 0.f;

    for (int cb = 0; cb < CPS; cb += 4) {
        int c0 = split * CPS + cb;
        float4 nb[9];
        #pragma unroll
        for (int r = 0; r < 9; r++)
            nb[r] = *reinterpret_cast<const float4*>(nbase[r] + c0);
        #pragma unroll
        for (int n = 0; n < 9; n++) {
            float mn = msk[n];
            #pragma unroll
            for (int cl = 0; cl < 4; cl++) {
                float xv = ((const float*)&nb[n])[cl] * mn;
                const float* wcn = wt + ((size_t)(c0 + cl) * 9 + n) * 32;
                #pragma unroll
                for (int o = 0; o < 27; o++)
                    acc[o] = fmaf(wcn[o], xv, acc[o]);
            }
        }
    }

    float* pb = part + (((size_t)split * BATCH + b) * 27) * HW + pix;
    #pragma unroll
    for (int o = 0; o < 27; o++) pb[(size_t)o * HW] = acc[o];
}

// ---------------------------------------------------------------------------
// Reduce 4 channel-split partials, add bias, sigmoid mask channels.
// out: [B][27][HW]  (0..17 offsets, 18..26 mask)
// ---------------------------------------------------------------------------
__global__ __launch_bounds__(256) void conv_off_reduce(
    const float* __restrict__ part, const float* __restrict__ bp,
    const float* __restrict__ bm, float* __restrict__ out)
{
    int t4 = blockIdx.x * 256 + threadIdx.x;
    if (t4 >= BATCH * 27 * HW / 4) return;
    int t   = t4 * 4;
    int b   = t / (27 * HW);
    int rem = t - b * 27 * HW;
    int oc  = rem / HW;
    int pix = rem - oc * HW;

    float4 s = make_float4(0.f, 0.f, 0.f, 0.f);
    #pragma unroll
    for (int sp = 0; sp < 4; sp++) {
        float4 v = *reinterpret_cast<const float4*>(
            part + (((size_t)sp * BATCH + b) * 27 + oc) * HW + pix);
        s.x += v.x; s.y += v.y; s.z += v.z; s.w += v.w;
    }
    if (oc < 18) {
        float bv = bp[oc];
        s.x += bv; s.y += bv; s.z += bv; s.w += bv;
    } else {
        float bv = bm[oc - 18];
        s.x = sigmoidf_(s.x + bv); s.y = sigmoidf_(s.y + bv);
        s.z = sigmoidf_(s.z + bv); s.w = sigmoidf_(s.w + bv);
    }
    *reinterpret_cast<float4*>(out + ((size_t)b * 27 + oc) * HW + pix) = s;
}

// ---------------------------------------------------------------------------
// Deformable sampling + main conv via MFMA (bf16 inputs, fp32 accum).
// Block: 64 pix x 64 oc, 512 threads (8 waves: 2 oc-halves x 4 pix-quarters).
// K layout per 8-channel chunk: k' = n*8 + cl, n 0..8 (+pad 9..11), cl 0..7.
// LDS: double-buffered wbuf/sbuf [64][104] bf16 (stride 104 -> <=2-way banks);
// meta (4x u16 idx + 4x bf16 wt per (tap,pix)) computed once per block.
// Schedule per chunk: MFMA(cur) reads first, then sample/stage(next), barrier.
// ---------------------------------------------------------------------------
template<int CIN>
__global__ __launch_bounds__(512, 4) void deform_mfma(
    const float* __restrict__ xt,           // [B][HW][CIN]
    const float* __restrict__ off,          // [B][27][HW]
    const unsigned short* __restrict__ wtp, // [64][NCH*96] bf16
    float* __restrict__ out)                // [B][64][HW]
{
    constexpr int NCH  = CIN / 8;
    constexpr int SROW = 104;
    __shared__ __align__(16) unsigned short sbuf[2][64][SROW];
    __shared__ __align__(16) unsigned short wbuf[2][64][SROW];
    __shared__ __align__(16) unsigned short meta[9][64][8];

    int tid  = threadIdx.x;
    int pix0 = blockIdx.x * 64;
    int b    = pix0 >> 14;
    int base = pix0 & (HW - 1);
    int i    = base >> 7;
    int j0   = base & 127;

    // ---- bilinear metadata (once per block) ----
    for (int task = tid; task < 576; task += 512) {
        int p = task & 63, n = task >> 6;
        int j = j0 + p;
        const float* ob = off + (size_t)b * 27 * HW + (i << 7) + j;
        float px = ob[(size_t)n * HW]       + (float)(n / 3 - 1) + (float)(i + 1);
        float py = ob[(size_t)(9 + n) * HW] + (float)(n % 3 - 1) + (float)(j + 1);
        float mk = ob[(size_t)(18 + n) * HW];
        float fx = floorf(px), fy = floorf(py);
        const float lim = 129.0f;            // Hp-1 = Wp-1
        int qltx = (int)fminf(fmaxf(fx, 0.f), lim);
        int qlty = (int)fminf(fmaxf(fy, 0.f), lim);
        int qrbx = (int)fminf(fmaxf(fx + 1.f, 0.f), lim);
        int qrby = (int)fminf(fmaxf(fy + 1.f, 0.f), lim);
        float pxc = fminf(fmaxf(px, 0.f), lim);
        float pyc = fminf(fmaxf(py, 0.f), lim);
        float gxl = 1.f + ((float)qltx - pxc);
        float gxr = 1.f - ((float)qrbx - pxc);
        float gyl = 1.f + ((float)qlty - pyc);
        float gyr = 1.f - ((float)qrby - pyc);
        int   xs[4] = {qltx, qrbx, qltx, qrbx};
        int   ys[4] = {qlty, qrby, qrby, qlty};
        float gs[4] = {gxl * gyl, gxr * gyr, gxl * gyr, gxr * gyl};
        u16x8 m;
        #pragma unroll
        for (int q = 0; q < 4; q++) {
            int qx = xs[q], qy = ys[q];
            bool valid = (qx >= 1 && qx <= H && qy >= 1 && qy <= W);
            m[q]     = valid ? (unsigned short)((qx - 1) * W + (qy - 1)) : (unsigned short)0;
            m[4 + q] = f2bf(valid ? gs[q] * mk : 0.f);
        }
        *reinterpret_cast<u16x8*>(&meta[n][p][0]) = m;
    }
    // ---- zero-init pad k-slots (72..95) of both sample buffers ----
    for (int idx = tid; idx < 2 * 64 * 3; idx += 512) {
        int bi = idx / 192;
        int r2 = idx - bi * 192;
        int row = r2 / 3, sg = r2 - (r2 / 3) * 3;
        u16x8 z = {0,0,0,0,0,0,0,0};
        *reinterpret_cast<u16x8*>(&sbuf[bi][row][72 + sg * 8]) = z;
    }
    __syncthreads();

    auto stage_w = [&](int ch, int bi) {
        #pragma unroll
        for (int pass = 0; pass < 2; pass++) {
            int idx = pass * 512 + tid;
            int row = idx >> 4, seg = idx & 15;
            if (seg < 12) {
                u16x8 v = *reinterpret_cast<const u16x8*>(
                    wtp + (size_t)row * (NCH * 96) + ch * 96 + seg * 8);
                *reinterpret_cast<u16x8*>(&wbuf[bi][row][seg * 8]) = v;
            }
        }
    };
    auto sample = [&](int ch, int bi) {
        for (int task = tid; task < 576; task += 512) {
            int p = task & 63, n = task >> 6;
            u16x8 m = *reinterpret_cast<const u16x8*>(&meta[n][p][0]);
            float vac[8];
            #pragma unroll
            for (int e = 0; e < 8; e++) vac[e] = 0.f;
            #pragma unroll
            for (int q = 0; q < 4; q++) {
                const float* srcp = xt + ((size_t)b * HW + m[q]) * CIN + ch * 8;
                float wq = bf2f(m[4 + q]);
                float4 lo = *reinterpret_cast<const float4*>(srcp);
                float4 hi = *reinterpret_cast<const float4*>(srcp + 4);
                vac[0] = fmaf(lo.x, wq, vac[0]);
                vac[1] = fmaf(lo.y, wq, vac[1]);
                vac[2] = fmaf(lo.z, wq, vac[2]);
                vac[3] = fmaf(lo.w, wq, vac[3]);
                vac[4] = fmaf(hi.x, wq, vac[4]);
                vac[5] = fmaf(hi.y, wq, vac[5]);
                vac[6] = fmaf(hi.z, wq, vac[6]);
                vac[7] = fmaf(hi.w, wq, vac[7]);
            }
            u16x8 o;
            #pragma unroll
            for (int e = 0; e < 8; e++) o[e] = f2bf(vac[e]);
            *reinterpret_cast<u16x8*>(&sbuf[bi][p][n * 8]) = o;
        }
    };

    // prologue: fill chunk 0
    stage_w(0, 0);
    sample(0, 0);
    __syncthreads();

    int lane = tid & 63, wv = tid >> 6;
    int ocq = wv & 1, pq = wv >> 1;
    int lr = lane & 15, lg = lane >> 4;
    int srow = pq * 16 + lr;
    int wrow = ocq * 32 + lr;

    f32x4 acc0 = {0.f, 0.f, 0.f, 0.f};
    f32x4 acc1 = {0.f, 0.f, 0.f, 0.f};

    for (int ch = 0; ch < NCH; ch++) {
        int cur = ch & 1;
        #pragma unroll
        for (int ks = 0; ks < 3; ks++) {
            bf16x8 bfr = *reinterpret_cast<const bf16x8*>(&sbuf[cur][srow][ks * 32 + lg * 8]);
            bf16x8 a0  = *reinterpret_cast<const bf16x8*>(&wbuf[cur][wrow][ks * 32 + lg * 8]);
            bf16x8 a1  = *reinterpret_cast<const bf16x8*>(&wbuf[cur][wrow + 16][ks * 32 + lg * 8]);
            acc0 = __builtin_amdgcn_mfma_f32_16x16x32_bf16(a0, bfr, acc0, 0, 0, 0);
            acc1 = __builtin_amdgcn_mfma_f32_16x16x32_bf16(a1, bfr, acc1, 0, 0, 0);
        }
        if (ch + 1 < NCH) {
            sample(ch + 1, cur ^ 1);
            stage_w(ch + 1, cur ^ 1);
        }
        __syncthreads();
    }

    // ---- store: D col = lane&15 (pixel), row = (lane>>4)*4 + r (oc) ----
    int pixo = base + pq * 16 + lr;
    float* ob0 = out + ((size_t)b * 64 + ocq * 32 + lg * 4) * HW + pixo;
    #pragma unroll
    for (int r = 0; r < 4; r++) ob0[(size_t)r * HW] = acc0[r];
    float* ob1 = out + ((size_t)b * 64 + ocq * 32 + 16 + lg * 4) * HW + pixo;
    #pragma unroll
    for (int r = 0; r < 4; r++) ob1[(size_t)r * HW] = acc1[r];
}

// ---------------------------------------------------------------------------
// Group-norm statistics. One block per (b, group); 4 consecutive channels.
// ---------------------------------------------------------------------------
__global__ __launch_bounds__(256) void gn_stats(
    const float* __restrict__ buf, float* __restrict__ stats)
{
    int bg = blockIdx.x;
    const float4* v = reinterpret_cast<const float4*>(buf + (size_t)bg * 4 * HW);
    float sum = 0.f, ssq = 0.f;
    for (int idx = threadIdx.x; idx < 4 * HW / 4; idx += 256) {
        float4 x = v[idx];
        sum += x.x + x.y + x.z + x.w;
        ssq += x.x * x.x + x.y * x.y + x.z * x.z + x.w * x.w;
    }
    #pragma unroll
    for (int d = 32; d > 0; d >>= 1) {
        sum += __shfl_down(sum, d);
        ssq += __shfl_down(ssq, d);
    }
    __shared__ float ws1[4], ws2[4];
    int wid = threadIdx.x >> 6;
    if ((threadIdx.x & 63) == 0) { ws1[wid] = sum; ws2[wid] = ssq; }
    __syncthreads();
    if (threadIdx.x == 0) {
        float S = ws1[0] + ws1[1] + ws1[2] + ws1[3];
        float Q = ws2[0] + ws2[1] + ws2[2] + ws2[3];
        float mean = S * (1.0f / (4.0f * HW));
        float var  = Q * (1.0f / (4.0f * HW)) - mean * mean;
        stats[bg]      = mean;
        stats[32 + bg] = rsqrtf(var + 1e-5f);
    }
}

// ---------------------------------------------------------------------------
// Apply GN+relu -> c1, and produce channel mean & max maps.
// ---------------------------------------------------------------------------
__global__ __launch_bounds__(256) void gn_apply_meanmax(
    const float* __restrict__ dc, const float* __restrict__ stats,
    const float* __restrict__ gamma, const float* __restrict__ beta,
    float* __restrict__ c1, float* __restrict__ cm, float* __restrict__ cx)
{
    int t = blockIdx.x * 256 + threadIdx.x;
    if (t >= BATCH * HW) return;
    int b = t >> 14;
    int pix = t & (HW - 1);
    float msum = 0.f, mmax = -INFINITY;
    for (int c = 0; c < 64; c++) {
        int g = c >> 2;
        float mean = stats[b * 16 + g];
        float rstd = stats[32 + b * 16 + g];
        size_t idx = ((size_t)b * 64 + c) * HW + pix;
        float v = (dc[idx] - mean) * rstd * gamma[c] + beta[c];
        v = fmaxf(v, 0.f);
        c1[idx] = v;
        msum += v;
        mmax = fmaxf(mmax, v);
    }
    cm[t] = msum * (1.0f / 64.0f);
    cx[t] = mmax;
}

// ---------------------------------------------------------------------------
// Spatial-attention 1-ch 3x3 convs + sigmoid, scale & concat.
// OUTPUT IS CHANNEL-MAJOR: catt [B][HW][128]  (feeds stage-2 directly)
// ---------------------------------------------------------------------------
__global__ __launch_bounds__(256) void attn_cat(
    const float* __restrict__ c1, const float* __restrict__ cm,
    const float* __restrict__ cx,
    const float* __restrict__ wa, const float* __restrict__ ba,
    const float* __restrict__ wb, const float* __restrict__ bb,
    float* __restrict__ catt)
{
    int t = blockIdx.x * 256 + threadIdx.x;
    if (t >= BATCH * HW) return;
    int b = t >> 14;
    int pix = t & (HW - 1);
    int i = pix >> 7, j = pix & (W - 1);
    float sa = ba[0], sb = bb[0];
    #pragma unroll
    for (int di = 0; di < 3; di++) {
        int ii = i + di - 1;
        if (ii < 0 || ii >= H) continue;
        #pragma unroll
        for (int dj = 0; dj < 3; dj++) {
            int jj = j + dj - 1;
            if (jj < 0 || jj >= W) continue;
            int q = (b << 14) + (ii << 7) + jj;
            sa = fmaf(cm[q], wa[di * 3 + dj], sa);
            sb = fmaf(cx[q], wb[di * 3 + dj], sb);
        }
    }
    float av = sigmoidf_(sa);
    float mv = sigmoidf_(sb);
    float* cr = catt + (size_t)t * 128;
    #pragma unroll
    for (int c4 = 0; c4 < 16; c4++) {
        float4 v;
        v.x = c1[((size_t)b * 64 + c4 * 4 + 0) * HW + pix];
        v.y = c1[((size_t)b * 64 + c4 * 4 + 1) * HW + pix];
        v.z = c1[((size_t)b * 64 + c4 * 4 + 2) * HW + pix];
        v.w = c1[((size_t)b * 64 + c4 * 4 + 3) * HW + pix];
        float4 a = make_float4(v.x * av, v.y * av, v.z * av, v.w * av);
        float4 m = make_float4(v.x * mv, v.y * mv, v.z * mv, v.w * mv);
        *reinterpret_cast<float4*>(cr + c4 * 4)      = a;
        *reinterpret_cast<float4*>(cr + 64 + c4 * 4) = m;
    }
}

// ---------------------------------------------------------------------------
// Final GN + relu -> d_out (elementwise)
// ---------------------------------------------------------------------------
__global__ __launch_bounds__(256) void gn_final(
    const float* __restrict__ dc, const float* __restrict__ stats,
    const float* __restrict__ gamma, const float* __restrict__ beta,
    float* __restrict__ out)
{
    int t = blockIdx.x * 256 + threadIdx.x;
    if (t >= BATCH * 64 * HW) return;
    int c = (t >> 14) & 63;
    int b = t >> 20;
    int g = c >> 2;
    float mean = stats[b * 16 + g];
    float rstd = stats[32 + b * 16 + g];
    float v = (dc[t] - mean) * rstd * gamma[c] + beta[c];
    out[t] = fmaxf(v, 0.f);
}

// ---------------------------------------------------------------------------
extern "C" void kernel_launch(void* const* d_in, const int* in_sizes, int n_in,
                              void* d_out, int out_size, void* d_ws, size_t ws_size,
                              hipStream_t stream) {
    (void)in_sizes; (void)n_in; (void)out_size; (void)ws_size;
    const float* x   = (const float*)d_in[0];
    const float* wp1 = (const float*)d_in[1];
    const float* bp1 = (const float*)d_in[2];
    const float* wm1 = (const float*)d_in[3];
    const float* bm1 = (const float*)d_in[4];
    const float* wc1 = (const float*)d_in[5];
    const float* g1  = (const float*)d_in[6];
    const float* be1 = (const float*)d_in[7];
    const float* wa  = (const float*)d_in[8];
    const float* ba  = (const float*)d_in[9];
    const float* wb  = (const float*)d_in[10];
    const float* bb  = (const float*)d_in[11];
    const float* wp2 = (const float*)d_in[12];
    const float* bp2 = (const float*)d_in[13];
    const float* wm2 = (const float*)d_in[14];
    const float* bm2 = (const float*)d_in[15];
    const float* wc2 = (const float*)d_in[16];
    const float* g2  = (const float*)d_in[17];
    const float* be2 = (const float*)d_in[18];
    float* out = (float*)d_out;

    // ---- workspace layout (floats) ----
    float* ws   = (float*)d_ws;
    float* offb = ws;                          //  884736
    float* dcb  = offb + 2 * 27 * HW;          // 2097152
    float* c1b  = dcb + 2 * 64 * HW;           // 2097152
    float* cmb  = c1b + 2 * 64 * HW;           //   32768
    float* cxb  = cmb + 2 * HW;                //   32768
    float* catt = cxb + 2 * HW;                // 4194304  [B][HW][128]
    float* stb  = catt + (size_t)2 * 128 * HW; //      64
    float* wo1  = stb + 64;                    //   18432
    float* wo2  = wo1 + 64 * 9 * 32;           //   36864
    unsigned short* wtp1 = (unsigned short*)(wo2 + 128 * 9 * 32); // 64*8*96  u16
    unsigned short* wtp2 = wtp1 + 64 * 8 * 96;                    // 64*16*96 u16
    // conv partials (4*2*27*HW floats) alias dcb+c1b (dead at that point)
    float* partb = dcb;
    // x transposed [B][HW][64] lives in d_out scratch (rewritten by gn_final)
    float* xt1 = out;

    const int NPIXB = (BATCH * HW + 255) / 256;      // 128
    const int NCONV = NPIXB * 4;                     // 512
    const int NRED  = (BATCH * 27 * HW / 4 + 255) / 256;
    const int NDEF  = BATCH * HW / 64;               // 512

    // ---- weight prep + input transpose ----
    transpose_x64<<<512, 256, 0, stream>>>(x, xt1);
    transpose_wpad<64><<<(64 * 8 * 96 + 255) / 256, 256, 0, stream>>>(wc1, wtp1);
    transpose_wpad<128><<<(64 * 16 * 96 + 255) / 256, 256, 0, stream>>>(wc2, wtp2);
    transpose_woff<64><<<(27 * 64 * 9 + 255) / 256, 256, 0, stream>>>(wp1, wm1, wo1);
    transpose_woff<128><<<(27 * 128 * 9 + 255) / 256, 256, 0, stream>>>(wp2, wm2, wo2);

    // ---- stage 1 ----
    conv_off_part<64><<<NCONV, 256, 0, stream>>>(xt1, wo1, partb);
    conv_off_reduce<<<NRED, 256, 0, stream>>>(partb, bp1, bm1, offb);
    deform_mfma<64><<<NDEF, 512, 0, stream>>>(xt1, offb, wtp1, dcb);
    gn_stats<<<32, 256, 0, stream>>>(dcb, stb);
    gn_apply_meanmax<<<NPIXB, 256, 0, stream>>>(dcb, stb, g1, be1, c1b, cmb, cxb);
    attn_cat<<<NPIXB, 256, 0, stream>>>(c1b, cmb, cxb, wa, ba, wb, bb, catt);

    // ---- stage 2 ----
    conv_off_part<128><<<NCONV, 256, 0, stream>>>(catt, wo2, partb);
    conv_off_reduce<<<NRED, 256, 0, stream>>>(partb, bp2, bm2, offb);
    deform_mfma<128><<<NDEF, 512, 0, stream>>>(catt, offb, wtp2, dcb);
    gn_stats<<<32, 256, 0, stream>>>(dcb, stb);
    gn_final<<<(BATCH * 64 * HW + 255) / 256, 256, 0, stream>>>(dcb, stb, g2, be2, out);
}